// Round 1
// baseline (636.642 us; speedup 1.0000x reference)
//
#include <hip/hip_runtime.h>
#include <stdint.h>

#define TPB 256
#define RPT 4
#define NL 4

typedef _Float16 half2v __attribute__((ext_vector_type(2)));

static __device__ __forceinline__ uint32_t packh2(float a, float b) {
  half2v h;
  h.x = (_Float16)a;
  h.y = (_Float16)b;
  return __builtin_bit_cast(uint32_t, h);
}
static __device__ __forceinline__ float2 unpackh2(uint32_t u) {
  half2v h = __builtin_bit_cast(half2v, u);
  return make_float2((float)h.x, (float)h.y);
}
static __device__ __forceinline__ float fdot2h(uint32_t a, uint32_t b, float c) {
#if __has_builtin(__builtin_amdgcn_fdot2)
  return __builtin_amdgcn_fdot2(__builtin_bit_cast(half2v, a),
                                __builtin_bit_cast(half2v, b), c, false);
#else
  half2v x = __builtin_bit_cast(half2v, a);
  half2v y = __builtin_bit_cast(half2v, b);
  return c + (float)x.x * (float)y.x + (float)x.y * (float)y.y;
#endif
}

// Pack ff1_w as wpk1[l][dp][o]  = half2(W1[o][2dp], W1[o][2dp+1])   (8192 u32)
// Pack ff2_w as wpk2[l][o][dhp] = half2(W2[o][2dhp], W2[o][2dhp+1]) (8192 u32)
__global__ void pack_weights_kernel(const float* __restrict__ ff1_w,
                                    const float* __restrict__ ff2_w,
                                    uint32_t* __restrict__ wpk1,
                                    uint32_t* __restrict__ wpk2) {
  int idx = blockIdx.x * blockDim.x + threadIdx.x;
  if (idx < 8192) {
    int l = idx >> 11, dp = (idx >> 6) & 31, o = idx & 63;
    wpk1[idx] = packh2(ff1_w[(l * 64 + o) * 64 + 2 * dp],
                       ff1_w[(l * 64 + o) * 64 + 2 * dp + 1]);
  } else if (idx < 16384) {
    int j = idx - 8192;
    int l = j >> 11, o = (j >> 5) & 63, dhp = j & 31;
    wpk2[j] = packh2(ff2_w[(l * 64 + o) * 64 + 2 * dhp],
                     ff2_w[(l * 64 + o) * 64 + 2 * dhp + 1]);
  }
}

__global__ __launch_bounds__(TPB, 2) void aat_kernel(
    const int* __restrict__ tokens, const float* __restrict__ emb,
    const float* __restrict__ lin_w, const float* __restrict__ lin_b,
    const float* __restrict__ ff1_b, const float* __restrict__ ff2_b,
    const float* __restrict__ n1_g, const float* __restrict__ n1_b,
    const float* __restrict__ n2_g, const float* __restrict__ n2_b,
    const float* __restrict__ out_w, const float* __restrict__ out_b,
    const uint32_t* __restrict__ wpk1, const uint32_t* __restrict__ wpk2,
    float* __restrict__ out) {
  // y/t2 buffer: [pair][thread] -> consecutive lanes hit consecutive banks.
  __shared__ uint32_t ybuf[32 * TPB];                 // 32 KiB
  __shared__ float red4[4][64];
  __shared__ float avgbuf[64];
  __shared__ __align__(8) float attnbuf[64];

  const int t = threadIdx.x;
  const int b = blockIdx.x;
  const int lane = t & 63;
  const int wv = t >> 6;

  uint32_t xpk[RPT][32];  // x rows, packed f16 pairs, register-resident

  // ---------------- embed * sqrt(d) + positional encoding ----------------
  #pragma unroll
  for (int r = 0; r < RPT; r++) {
    int s = t + r * TPB;
    if (s < 1000) {
      int tok = tokens[b * 1000 + s];
      const float4* ev = (const float4*)(emb + (size_t)tok * 64);
      #pragma unroll
      for (int q = 0; q < 16; q++) {
        float4 v4 = ev[q];
        float xv[4] = {v4.x, v4.y, v4.z, v4.w};
        #pragma unroll
        for (int j = 0; j < 4; j++) {
          int d = 4 * q + j;
          // div_i = 10000^(-i/32), i = d>>1 ; log2(10000)/32 = 0.41524101186
          float div = exp2f(-0.4152410118609203f * (float)(d >> 1));
          float ang = (float)s * div;
          float pe = (d & 1) ? cosf(ang) : sinf(ang);
          xv[j] = xv[j] * 8.0f + pe;
        }
        xpk[r][2 * q] = packh2(xv[0], xv[1]);
        xpk[r][2 * q + 1] = packh2(xv[2], xv[3]);
      }
    } else {
      #pragma unroll
      for (int dp = 0; dp < 32; dp++) xpk[r][dp] = 0u;  // masked rows stay 0
    }
  }

  for (int l = 0; l < NL; l++) {
    // ---------------- avg over sequence: butterfly reduce ----------------
    float v[64];
    #pragma unroll
    for (int dp = 0; dp < 32; dp++) {
      float s0 = 0.f, s1 = 0.f;
      #pragma unroll
      for (int r = 0; r < RPT; r++) {
        if (t + r * TPB < 1000) {  // masked rows contribute 0
          float2 xv = unpackh2(xpk[r][dp]);
          s0 += xv.x;
          s1 += xv.y;
        }
      }
      v[2 * dp] = s0;
      v[2 * dp + 1] = s1;
    }
    // 6-stage butterfly: lane ends holding channel==lane summed over wave
    #pragma unroll
    for (int m = 32; m >= 1; m >>= 1) {
      #pragma unroll
      for (int k = 0; k < m; k++) {
        bool up = (lane & m) != 0;
        float send = up ? v[k] : v[k + m];
        float keep = up ? v[k + m] : v[k];
        v[k] = keep + __shfl_xor(send, m, 64);
      }
    }
    __syncthreads();
    red4[wv][lane] = v[0];
    __syncthreads();
    if (t < 64)
      avgbuf[t] = (red4[0][t] + red4[1][t] + red4[2][t] + red4[3][t]) * 1e-3f;
    __syncthreads();
    if (t < 64) {  // attn[o] = lin_b[o] + sum_d avg[d]*lin_w[o][d]
      const float* wr = lin_w + (size_t)(l * 64 + t) * 64;
      float a0 = lin_b[l * 64 + t], a1 = 0.f, a2 = 0.f, a3 = 0.f;
      #pragma unroll
      for (int d = 0; d < 64; d += 4) {
        a0 += avgbuf[d] * wr[d];
        a1 += avgbuf[d + 1] * wr[d + 1];
        a2 += avgbuf[d + 2] * wr[d + 2];
        a3 += avgbuf[d + 3] * wr[d + 3];
      }
      attnbuf[t] = (a0 + a1) + (a2 + a3);
    }
    __syncthreads();

    // ---------------- per-row: LN1 -> FF -> LN2 ----------------
    #pragma unroll
    for (int r = 0; r < RPT; r++) {
      // LN1 stats over t = x + attn
      float m0 = 0.f, m1 = 0.f, q0 = 0.f, q1 = 0.f;
      #pragma unroll
      for (int dp = 0; dp < 32; dp++) {
        float2 xv = unpackh2(xpk[r][dp]);
        float2 at = ((const float2*)attnbuf)[dp];
        float a0 = xv.x + at.x, a1 = xv.y + at.y;
        m0 += a0;
        m1 += a1;
        q0 = fmaf(a0, a0, q0);
        q1 = fmaf(a1, a1, q1);
      }
      float mu = (m0 + m1) * (1.0f / 64.0f);
      float var = (q0 + q1) * (1.0f / 64.0f) - mu * mu;
      float rs = rsqrtf(var + 1e-5f);
      // LN1 normalize -> ybuf (f16 pairs)
      #pragma unroll
      for (int dp = 0; dp < 32; dp++) {
        float2 xv = unpackh2(xpk[r][dp]);
        float2 at = ((const float2*)attnbuf)[dp];
        float a0 = xv.x + at.x, a1 = xv.y + at.y;
        float y0 = fmaf((a0 - mu) * rs, n1_g[l * 64 + 2 * dp], n1_b[l * 64 + 2 * dp]);
        float y1 = fmaf((a1 - mu) * rs, n1_g[l * 64 + 2 * dp + 1], n1_b[l * 64 + 2 * dp + 1]);
        ybuf[dp * TPB + t] = packh2(y0, y1);
      }
      // mm1: h = relu(y @ W1^T + b1); 64 independent acc chains, scalar weights
      float acc[64];
      #pragma unroll
      for (int o = 0; o < 64; o++) acc[o] = ff1_b[l * 64 + o];
      for (int dp = 0; dp < 32; dp++) {
        uint32_t y2 = ybuf[dp * TPB + t];
        const uint32_t* wr = wpk1 + (l * 32 + dp) * 64;
        #pragma unroll
        for (int o = 0; o < 64; o++) acc[o] = fdot2h(y2, wr[o], acc[o]);
      }
      uint32_t hpk[32];
      #pragma unroll
      for (int dp = 0; dp < 32; dp++)
        hpk[dp] = packh2(fmaxf(acc[2 * dp], 0.f), fmaxf(acc[2 * dp + 1], 0.f));
      // mm2 + residual (in-place into ybuf) + LN2 stats
      float mm0 = 0.f, mm1v = 0.f, qq0 = 0.f, qq1 = 0.f;
      for (int op = 0; op < 32; op++) {
        const uint32_t* w0 = wpk2 + (size_t)(l * 64 + 2 * op) * 32;
        const uint32_t* w1 = w0 + 32;
        float a0 = ff2_b[l * 64 + 2 * op], a1 = ff2_b[l * 64 + 2 * op + 1];
        float b0 = 0.f, b1v = 0.f;
        #pragma unroll
        for (int dhp = 0; dhp < 32; dhp += 2) {
          a0 = fdot2h(hpk[dhp], w0[dhp], a0);
          b0 = fdot2h(hpk[dhp + 1], w0[dhp + 1], b0);
          a1 = fdot2h(hpk[dhp], w1[dhp], a1);
          b1v = fdot2h(hpk[dhp + 1], w1[dhp + 1], b1v);
        }
        a0 += b0;
        a1 += b1v;
        float2 yv = unpackh2(ybuf[op * TPB + t]);
        a0 += yv.x;
        a1 += yv.y;
        mm0 += a0;
        mm1v += a1;
        qq0 = fmaf(a0, a0, qq0);
        qq1 = fmaf(a1, a1, qq1);
        ybuf[op * TPB + t] = packh2(a0, a1);
      }
      mu = (mm0 + mm1v) * (1.0f / 64.0f);
      var = (qq0 + qq1) * (1.0f / 64.0f) - mu * mu;
      rs = rsqrtf(var + 1e-5f);
      // LN2 normalize -> xpk (next layer's x)
      #pragma unroll
      for (int dp = 0; dp < 32; dp++) {
        float2 tv = unpackh2(ybuf[dp * TPB + t]);
        float x0 = fmaf((tv.x - mu) * rs, n2_g[l * 64 + 2 * dp], n2_b[l * 64 + 2 * dp]);
        float x1 = fmaf((tv.y - mu) * rs, n2_g[l * 64 + 2 * dp + 1], n2_b[l * 64 + 2 * dp + 1]);
        xpk[r][dp] = packh2(x0, x1);
      }
    }
  }

  // ---------------- output projection [B,S,2] ----------------
  #pragma unroll
  for (int r = 0; r < RPT; r++) {
    int s = t + r * TPB;
    if (s < 1000) {
      float a0 = out_b[0], a1 = out_b[1];
      #pragma unroll
      for (int dp = 0; dp < 32; dp++) {
        float2 xv = unpackh2(xpk[r][dp]);
        a0 += xv.x * out_w[2 * dp] + xv.y * out_w[2 * dp + 1];
        a1 += xv.x * out_w[64 + 2 * dp] + xv.y * out_w[64 + 2 * dp + 1];
      }
      float2 res;
      res.x = a0;
      res.y = a1;
      *(float2*)(out + (size_t)(b * 1000 + s) * 2) = res;
    }
  }
}

extern "C" void kernel_launch(void* const* d_in, const int* in_sizes, int n_in,
                              void* d_out, int out_size, void* d_ws, size_t ws_size,
                              hipStream_t stream) {
  const int* tokens = (const int*)d_in[0];
  const float* emb = (const float*)d_in[1];
  const float* lin_w = (const float*)d_in[2];
  const float* lin_b = (const float*)d_in[3];
  const float* ff1_w = (const float*)d_in[4];
  const float* ff1_b = (const float*)d_in[5];
  const float* ff2_w = (const float*)d_in[6];
  const float* ff2_b = (const float*)d_in[7];
  const float* n1_g = (const float*)d_in[8];
  const float* n1_b = (const float*)d_in[9];
  const float* n2_g = (const float*)d_in[10];
  const float* n2_b = (const float*)d_in[11];
  const float* out_w = (const float*)d_in[12];
  const float* out_b = (const float*)d_in[13];
  float* out = (float*)d_out;

  uint32_t* wpk1 = (uint32_t*)d_ws;       // 32 KiB
  uint32_t* wpk2 = wpk1 + 4 * 32 * 64;    // 32 KiB

  pack_weights_kernel<<<64, TPB, 0, stream>>>(ff1_w, ff2_w, wpk1, wpk2);
  aat_kernel<<<512, TPB, 0, stream>>>(tokens, emb, lin_w, lin_b, ff1_b, ff2_b,
                                      n1_g, n1_b, n2_g, n2_b, out_w, out_b,
                                      wpk1, wpk2, out);
}